// Round 14
// baseline (269.570 us; speedup 1.0000x reference)
//
#include <hip/hip_runtime.h>

#define T_LEN 100
#define H 32
#define L 6
#define NT 6          // 96 gate rows / 16
#define TPB 512       // 8 waves: SIMD s hosts waves {s, s+4}
#define BT 32         // two independent 16-batch groups per block
#define NPAIR 25      // four timesteps per barrier interval
#define NK (NPAIR + L - 1)   // 30 intervals, layer skew d = layer
#define S1 1.44269504088896f   // log2(e)

typedef float f32x4  __attribute__((ext_vector_type(4)));
typedef _Float16 f16x8 __attribute__((ext_vector_type(8)));

union FragU { f16x8 h; f32x4 f; unsigned int u[4]; };

__device__ inline unsigned short f2h(float f) {
    union { _Float16 h; unsigned short u; } v; v.h = (_Float16)f; return v.u;
}
__device__ inline float rcpa(float x)  { return __builtin_amdgcn_rcpf(x); }
__device__ inline float exp2b(float x) { return __builtin_amdgcn_exp2f(x); }

// pack f32 pair -> one u32 of 2 f16 (RTZ)
__device__ inline unsigned int pk16(float a, float b) {
    unsigned int h;
    asm("v_cvt_pkrtz_f16_f32 %0, %1, %2" : "=v"(h) : "v"(a), "v"(b));
    return h;
}

// ---- prep: pack weight A-fragments as f16 (matmul-operand quantization;
// the f32 recurrent state hp is never quantized), pre-scaled by -log2e /
// -2log2e, with kappa k-relabeling: hardware k-slot (gk*8+e) holds W column
// j = (e>>2)*16 + gk*4 + (e&3).  This makes MFMA C/D layout == B-frag layout.
__global__ void pack_frags(const float* __restrict__ Whh, const float* __restrict__ Wih,
                           unsigned short* __restrict__ WhFhi,
                           unsigned short* __restrict__ WiFhi)
{
    int tid = blockIdx.x * blockDim.x + threadIdx.x;
    const int NWH = L * NT * 64;          // 2304
    const int NWI = (L - 1) * NT * 64;    // 1920
    if (tid >= NWH + NWI) return;
    const float* src; unsigned short *dhi; int tile, lane;
    if (tid < NWH) {
        int l = tid / (NT * 64); int r = tid % (NT * 64); tile = r / 64; lane = r % 64;
        src = Whh + l * 96 * H;
        dhi = WhFhi + tid * 8;
    } else {
        int t2 = tid - NWH;
        int l = t2 / (NT * 64); int r = t2 % (NT * 64); tile = r / 64; lane = r % 64;
        src = Wih + l * 96 * H;           // W_ih[l] feeds layer l+1
        dhi = WiFhi + t2 * 8;
    }
    int row = tile * 16 + (lane & 15);
    int gk  = lane >> 4;
    float scale = (row < 64) ? -S1 : -2.0f * S1;
    unsigned short thi[8];
#pragma unroll
    for (int e = 0; e < 8; ++e) {
        int j = ((e >> 2) << 4) + (gk << 2) + (e & 3);   // kappa^-1
        thi[e] = f2h(scale * src[row * H + j]);
    }
    *(uint4*)dhi = *(const uint4*)thi;
}

// ---- main: 8-wave layer ladder, barrier-synced, four steps per interval,
// single-product f16 matmuls (R12 structure), plus INTERVAL-TOP READ HOIST:
// all 8 handoff ds_reads (4 steps x 2 groups, parity q) are issued before
// any LDS write of the interval.  Without this, the compiler cannot prove
// the parity-q reads don't alias the parity-p writes (XOR-swizzled offsets
// into one __shared__ array), so each step's read serializes behind the
// previous step's write and eats ~120 cyc of ds_read latency on the
// critical path.
// VALU-balanced wave map: SIMD pairs {L0,L1a} {L2,L1b} {L3,L5a} {L4,L5b}.
__global__ __launch_bounds__(TPB, 2) void gru_mfma(
    const float* __restrict__ x,          // [B][T]
    const float* __restrict__ Wih0,       // [96]
    const float* __restrict__ bih,        // [6][96]
    const float* __restrict__ bhh,        // [6][96]
    const unsigned short* __restrict__ WhFhi,
    const unsigned short* __restrict__ WiFhi,
    const float* __restrict__ Wk, const float* __restrict__ bk,
    const float* __restrict__ We, const float* __restrict__ be,
    const float* __restrict__ Wt, const float* __restrict__ bt,
    float* __restrict__ out, int B)
{
    // handoff slot per (layer 0..4, interval parity, step 0..3), 2 KB each:
    // grp0{hi 1K} grp1{hi 1K}.  row b = 64B; logical 16B-block c stored at
    // column c ^ ((b>>1)&3).
    __shared__ unsigned char slot[5][2][4][2048];   // 80 KB
    __shared__ float xt[T_LEN][BT];
    __shared__ float hpart[L][3][BT];

    const int tid  = threadIdx.x;
    const int wv   = tid >> 6;        // wave index
    const int lane = tid & 63;
    const int b    = lane & 15;       // batch col (MFMA N)
    const int g    = lane >> 4;       // k-group
    const int b0   = blockIdx.x * BT;

    // wave -> (layer, group-mask).  SIMD pairs {w0,w4} {w1,w5} {w2,w6}
    // {w3,w7}; L1 and L5 split in half so every SIMD carries 3 gate-units:
    //   S0:{L0, L1.g0}  S1:{L2, L1.g1}  S2:{L3, L5.g0}  S3:{L4, L5.g1}
    int layer, grmask;
    switch (wv) {
      case 0: layer = 0; grmask = 3; break;   // light scalar-input layer
      case 4: layer = 1; grmask = 1; break;
      case 1: layer = 2; grmask = 3; break;
      case 5: layer = 1; grmask = 2; break;
      case 2: layer = 3; grmask = 3; break;
      case 6: layer = 5; grmask = 1; break;
      case 3: layer = 4; grmask = 3; break;
      default: layer = 5; grmask = 2; break;  // w7
    }

    // stage x tile
    for (int idx = tid; idx < T_LEN * BT; idx += TPB) {
        int bb = idx / T_LEN, t = idx % T_LEN;
        xt[t][bb] = x[(b0 + bb) * T_LEN + t];
    }

    // weight fragments for my layer, held in registers all 100 steps
    f16x8 whh[NT], wih[NT];
#pragma unroll
    for (int t6 = 0; t6 < NT; ++t6)
        whh[t6] = ((const f16x8*)WhFhi)[(layer * NT + t6) * 64 + lane];
    if (layer > 0) {
#pragma unroll
        for (int t6 = 0; t6 < NT; ++t6)
            wih[t6] = ((const f16x8*)WiFhi)[((layer - 1) * NT + t6) * 64 + lane];
    }

    // pre-scaled biases in C/D layout (row = t6*16 + g*4 + r)
    f32x4 bc[4], bxn[2], bhn[2];
    {
        const int rb = g * 4;
#pragma unroll
        for (int t6 = 0; t6 < 4; ++t6)
#pragma unroll
            for (int r = 0; r < 4; ++r) {
                int row = t6 * 16 + rb + r;
                bc[t6][r] = -S1 * (bih[layer * 96 + row] + bhh[layer * 96 + row]);
            }
#pragma unroll
        for (int tt = 0; tt < 2; ++tt)
#pragma unroll
            for (int r = 0; r < 4; ++r) {
                int row = 64 + tt * 16 + rb + r;
                bxn[tt][r] = -2.0f * S1 * bih[layer * 96 + row];
                bhn[tt][r] = -2.0f * S1 * bhh[layer * 96 + row];
            }
        if (layer == 0) {
            // layer-0 wave never uses wih as frags: reuse for pre-scaled f32
            // input weights via the union view
#pragma unroll
            for (int t6 = 0; t6 < NT; ++t6) {
                FragU u;
#pragma unroll
                for (int r = 0; r < 4; ++r) {
                    int row = t6 * 16 + rb + r;
                    float s = (row < 64) ? -S1 : -2.0f * S1;
                    u.f[r] = s * Wih0[row];
                }
                wih[t6] = u.h;
            }
        }
    }

    float hp[2][8];
#pragma unroll
    for (int gr = 0; gr < 2; ++gr)
#pragma unroll
        for (int i = 0; i < 8; ++i) hp[gr][i] = 0.0f;
    f16x8 hfH[2] = {{0,0,0,0,0,0,0,0},{0,0,0,0,0,0,0,0}};

    // unified slot offset (read & write identical): row b, logical block g,
    // XOR-swizzled by (b>>1)&3.  Group gr adds gr*1024.
    const int soff = b * 64 + ((g ^ ((b >> 1) & 3)) << 4);
    unsigned char* const sbase = (unsigned char*)slot;

    // one GRU step for BOTH batch groups; handoff operands passed in
    // (pre-read at interval top).  wp = parity to write, st = step slot.
    auto do_step2 = [&](int t, int wp, int st, f16x8 iH0, f16x8 iH1) {
        f32x4 acc[2][4], accX[2][2], accH[2][2];
        // ---- MFMA phase: single product own-h (C-init = biases) ----
#pragma unroll
        for (int gr = 0; gr < 2; ++gr)
            if (grmask & (1 << gr)) {
#pragma unroll
                for (int t6 = 0; t6 < 4; ++t6)
                    acc[gr][t6] = __builtin_amdgcn_mfma_f32_16x16x32_f16(whh[t6], hfH[gr], bc[t6], 0, 0, 0);
#pragma unroll
                for (int tt = 0; tt < 2; ++tt)
                    accH[gr][tt] = __builtin_amdgcn_mfma_f32_16x16x32_f16(whh[4 + tt], hfH[gr], bhn[tt], 0, 0, 0);
            }
        // input product: wih x iH (hi-only handoff) / scalar x for layer 0
        if (layer == 0) {
#pragma unroll
            for (int gr = 0; gr < 2; ++gr)
                if (grmask & (1 << gr)) {
                    float xv = xt[t][gr * 16 + b];
#pragma unroll
                    for (int t6 = 0; t6 < 4; ++t6) {
                        FragU u; u.h = wih[t6];
#pragma unroll
                        for (int r = 0; r < 4; ++r)
                            acc[gr][t6][r] = fmaf(u.f[r], xv, acc[gr][t6][r]);
                    }
#pragma unroll
                    for (int tt = 0; tt < 2; ++tt) {
                        FragU u; u.h = wih[4 + tt];
#pragma unroll
                        for (int r = 0; r < 4; ++r)
                            accX[gr][tt][r] = fmaf(u.f[r], xv, bxn[tt][r]);
                    }
                }
        } else {
            if (grmask & 1) {
#pragma unroll
                for (int t6 = 0; t6 < 4; ++t6)
                    acc[0][t6] = __builtin_amdgcn_mfma_f32_16x16x32_f16(wih[t6], iH0, acc[0][t6], 0, 0, 0);
#pragma unroll
                for (int tt = 0; tt < 2; ++tt)
                    accX[0][tt] = __builtin_amdgcn_mfma_f32_16x16x32_f16(wih[4 + tt], iH0, bxn[tt], 0, 0, 0);
            }
            if (grmask & 2) {
#pragma unroll
                for (int t6 = 0; t6 < 4; ++t6)
                    acc[1][t6] = __builtin_amdgcn_mfma_f32_16x16x32_f16(wih[t6], iH1, acc[1][t6], 0, 0, 0);
#pragma unroll
                for (int tt = 0; tt < 2; ++tt)
                    accX[1][tt] = __builtin_amdgcn_mfma_f32_16x16x32_f16(wih[4 + tt], iH1, bxn[tt], 0, 0, 0);
            }
        }
        // ---- gate phase: both groups together (16 independent chains) ----
        // gates (pre-scaled): Er=e^-rpre, Ez=e^-zpre, En=e^-2npre
        // r = 1/(1+Er); n = (1-En)/(1+En); h = [n*Ez + hp] / (1+Ez)
#pragma unroll
        for (int gr = 0; gr < 2; ++gr)
            if (grmask & (1 << gr)) {
#pragma unroll
                for (int jj = 0; jj < 2; ++jj)
#pragma unroll
                    for (int r = 0; r < 4; ++r) {
                        float Er = exp2b(acc[gr][jj][r]);
                        float Ez = exp2b(acc[gr][2 + jj][r]);
                        float rg = rcpa(1.0f + Er);
                        float u  = fmaf(rg, accH[gr][jj][r], accX[gr][jj][r]);
                        float En = exp2b(u);
                        float en1 = 1.0f + En, ez1 = 1.0f + Ez;
                        float d   = rcpa(en1 * ez1);
                        float t2  = fmaf(-En, Ez, Ez);        // (1-En)*Ez, single-rounded
                        float num = fmaf(hp[gr][jj * 4 + r], en1, t2);
                        hp[gr][jj * 4 + r] = num * d;
                    }
            }
        // ---- pack + handoff write, both groups (hi only) ----
#pragma unroll
        for (int gr = 0; gr < 2; ++gr)
            if (grmask & (1 << gr)) {
                unsigned int h01 = pk16(hp[gr][0], hp[gr][1]);
                unsigned int h23 = pk16(hp[gr][2], hp[gr][3]);
                unsigned int h45 = pk16(hp[gr][4], hp[gr][5]);
                unsigned int h67 = pk16(hp[gr][6], hp[gr][7]);
                FragU Hu;
                Hu.u[0] = h01; Hu.u[1] = h23; Hu.u[2] = h45; Hu.u[3] = h67;
                hfH[gr] = Hu.h;
                if (layer < L - 1) {
                    unsigned char* wp8 = sbase + ((layer * 8 + wp * 4 + st) << 11) + gr * 1024;
                    *(uint4*)(wp8 + soff) = make_uint4(h01, h23, h45, h67);
                }
            }
    };

    __syncthreads();

    for (int i = 0; i < NK; ++i) {
        int k = i - layer;            // local 4-step chunk index
        if (0 <= k && k < NPAIR) {
            const int p = i & 1, q = p ^ 1;
            // interval-top read hoist: all parity-q handoff reads issued
            // before ANY parity-p write of this interval (see kernel comment)
            f16x8 ih[2][4] = {};
            if (layer > 0) {
                const unsigned char* ru = sbase + (((layer - 1) * 8 + q * 4) << 11);
#pragma unroll
                for (int st = 0; st < 4; ++st) {
                    if (grmask & 1) ih[0][st] = *(const f16x8*)(ru + (st << 11) + soff);
                    if (grmask & 2) ih[1][st] = *(const f16x8*)(ru + (st << 11) + 1024 + soff);
                }
            }
#pragma unroll
            for (int st = 0; st < 4; ++st)
                do_step2(4 * k + st, p, st, ih[0][st], ih[1][st]);
        }
        __syncthreads();
    }

    // heads: per-(layer,group) partial over 32 hidden units, then cross-wave reduce
    {
        const int rb = g * 4;
#pragma unroll
        for (int hd = 0; hd < 3; ++hd) {
            const float* W = (hd == 0) ? Wk : (hd == 1) ? We : Wt;
#pragma unroll
            for (int gr = 0; gr < 2; ++gr)
                if (grmask & (1 << gr)) {
                    float s = 0.0f;
#pragma unroll
                    for (int jj = 0; jj < 2; ++jj)
#pragma unroll
                        for (int r = 0; r < 4; ++r)
                            s = fmaf(W[layer * H + jj * 16 + rb + r], hp[gr][jj * 4 + r], s);
                    s += __shfl_xor(s, 16, 64);
                    s += __shfl_xor(s, 32, 64);
                    if (g == 0) hpart[layer][hd][gr * 16 + b] = s;
                }
        }
        __syncthreads();
        if (wv < 3 && lane < BT) {
            int bb = lane;
            float s = (wv == 0) ? bk[0] : (wv == 1) ? be[0] : bt[0];
#pragma unroll
            for (int l = 0; l < L; ++l) s += hpart[l][wv][bb];
            out[wv * B + b0 + bb] = s;
        }
    }
}

extern "C" void kernel_launch(void* const* d_in, const int* in_sizes, int n_in,
                              void* d_out, int out_size, void* d_ws, size_t ws_size,
                              hipStream_t stream)
{
    const float* x    = (const float*)d_in[0];
    const float* Wih0 = (const float*)d_in[1];
    const float* Wih  = (const float*)d_in[2];
    const float* Whh  = (const float*)d_in[3];
    const float* bih  = (const float*)d_in[4];
    const float* bhh  = (const float*)d_in[5];
    const float* Wk   = (const float*)d_in[6];
    const float* bk   = (const float*)d_in[7];
    const float* We   = (const float*)d_in[8];
    const float* be   = (const float*)d_in[9];
    const float* Wt   = (const float*)d_in[10];
    const float* bt   = (const float*)d_in[11];
    float* out = (float*)d_out;

    const int B = in_sizes[0] / T_LEN;   // 16384

    unsigned short* WhFhi = (unsigned short*)d_ws;        // 6*6*64*8 f16
    unsigned short* WiFhi = WhFhi + L * NT * 64 * 8;      // 5*6*64*8 f16

    const int nPack = (L * NT * 64) + ((L - 1) * NT * 64);  // 4224
    pack_frags<<<(nPack + 255) / 256, 256, 0, stream>>>(Whh, Wih, WhFhi, WiFhi);
    gru_mfma<<<B / BT, TPB, 0, stream>>>(x, Wih0, bih, bhh, WhFhi, WiFhi,
                                         Wk, bk, We, be, Wt, bt, out, B);
}

// Round 15
// 237.496 us; speedup vs baseline: 1.1351x; 1.1351x over previous
//
#include <hip/hip_runtime.h>

#define T_LEN 100
#define H 32
#define L 6
#define NT 6          // 96 gate rows / 16
#define TPB 512       // 8 waves: SIMD s hosts waves {s, s+4}
#define BT 32         // two independent 16-batch groups per block
#define NPAIR 25      // four timesteps per barrier interval
#define NK (NPAIR + L - 1)   // 30 intervals, layer skew d = layer
#define S1 1.44269504088896f   // log2(e)

typedef float f32x4  __attribute__((ext_vector_type(4)));
typedef _Float16 f16x8 __attribute__((ext_vector_type(8)));

union FragU { f16x8 h; f32x4 f; unsigned int u[4]; };

__device__ inline unsigned short f2h(float f) {
    union { _Float16 h; unsigned short u; } v; v.h = (_Float16)f; return v.u;
}
__device__ inline float rcpa(float x)  { return __builtin_amdgcn_rcpf(x); }
__device__ inline float exp2b(float x) { return __builtin_amdgcn_exp2f(x); }

// pack f32 pair -> one u32 of 2 f16 (RTZ)
__device__ inline unsigned int pk16(float a, float b) {
    unsigned int h;
    asm("v_cvt_pkrtz_f16_f32 %0, %1, %2" : "=v"(h) : "v"(a), "v"(b));
    return h;
}

// ---- prep: pack weight A-fragments as f16 (matmul-operand quantization;
// the f32 recurrent state hp is never quantized), pre-scaled by -log2e /
// -2log2e, with kappa k-relabeling: hardware k-slot (gk*8+e) holds W column
// j = (e>>2)*16 + gk*4 + (e&3).  This makes MFMA C/D layout == B-frag layout.
__global__ void pack_frags(const float* __restrict__ Whh, const float* __restrict__ Wih,
                           unsigned short* __restrict__ WhFhi,
                           unsigned short* __restrict__ WiFhi)
{
    int tid = blockIdx.x * blockDim.x + threadIdx.x;
    const int NWH = L * NT * 64;          // 2304
    const int NWI = (L - 1) * NT * 64;    // 1920
    if (tid >= NWH + NWI) return;
    const float* src; unsigned short *dhi; int tile, lane;
    if (tid < NWH) {
        int l = tid / (NT * 64); int r = tid % (NT * 64); tile = r / 64; lane = r % 64;
        src = Whh + l * 96 * H;
        dhi = WhFhi + tid * 8;
    } else {
        int t2 = tid - NWH;
        int l = t2 / (NT * 64); int r = t2 % (NT * 64); tile = r / 64; lane = r % 64;
        src = Wih + l * 96 * H;           // W_ih[l] feeds layer l+1
        dhi = WiFhi + t2 * 8;
    }
    int row = tile * 16 + (lane & 15);
    int gk  = lane >> 4;
    float scale = (row < 64) ? -S1 : -2.0f * S1;
    unsigned short thi[8];
#pragma unroll
    for (int e = 0; e < 8; ++e) {
        int j = ((e >> 2) << 4) + (gk << 2) + (e & 3);   // kappa^-1
        thi[e] = f2h(scale * src[row * H + j]);
    }
    *(uint4*)dhi = *(const uint4*)thi;
}

// ---- main: 8-wave layer ladder, barrier-synced, four steps per interval,
// SINGLE-PRODUCT f16 matmuls (the 244 us R12 structure -- both hand
// restructures of this step body regressed; the short-lived straight-line
// form schedules best).  s_setprio(1) wraps the MFMA phase: waves here are
// heterogeneous (different layers / L0 VALU-only), so SIMD partners are
// usually in different phases and priority lets the MFMA-entering wave
// claim issue slots against its partner's gate burst.
// VALU-balanced wave map: SIMD pairs {L0,L1a} {L2,L1b} {L3,L5a} {L4,L5b}.
__global__ __launch_bounds__(TPB, 2) void gru_mfma(
    const float* __restrict__ x,          // [B][T]
    const float* __restrict__ Wih0,       // [96]
    const float* __restrict__ bih,        // [6][96]
    const float* __restrict__ bhh,        // [6][96]
    const unsigned short* __restrict__ WhFhi,
    const unsigned short* __restrict__ WiFhi,
    const float* __restrict__ Wk, const float* __restrict__ bk,
    const float* __restrict__ We, const float* __restrict__ be,
    const float* __restrict__ Wt, const float* __restrict__ bt,
    float* __restrict__ out, int B)
{
    // handoff slot per (layer 0..4, interval parity, step 0..3), 2 KB each:
    // grp0{hi 1K} grp1{hi 1K}.  row b = 64B; logical 16B-block c stored at
    // column c ^ ((b>>1)&3).
    __shared__ unsigned char slot[5][2][4][2048];   // 80 KB
    __shared__ float xt[T_LEN][BT];
    __shared__ float hpart[L][3][BT];

    const int tid  = threadIdx.x;
    const int wv   = tid >> 6;        // wave index
    const int lane = tid & 63;
    const int b    = lane & 15;       // batch col (MFMA N)
    const int g    = lane >> 4;       // k-group
    const int b0   = blockIdx.x * BT;

    // wave -> (layer, group-mask).  SIMD pairs {w0,w4} {w1,w5} {w2,w6}
    // {w3,w7}; L1 and L5 split in half so every SIMD carries 3 gate-units:
    //   S0:{L0, L1.g0}  S1:{L2, L1.g1}  S2:{L3, L5.g0}  S3:{L4, L5.g1}
    int layer, grmask;
    switch (wv) {
      case 0: layer = 0; grmask = 3; break;   // light scalar-input layer
      case 4: layer = 1; grmask = 1; break;
      case 1: layer = 2; grmask = 3; break;
      case 5: layer = 1; grmask = 2; break;
      case 2: layer = 3; grmask = 3; break;
      case 6: layer = 5; grmask = 1; break;
      case 3: layer = 4; grmask = 3; break;
      default: layer = 5; grmask = 2; break;  // w7
    }

    // stage x tile
    for (int idx = tid; idx < T_LEN * BT; idx += TPB) {
        int bb = idx / T_LEN, t = idx % T_LEN;
        xt[t][bb] = x[(b0 + bb) * T_LEN + t];
    }

    // weight fragments for my layer, held in registers all 100 steps
    f16x8 whh[NT], wih[NT];
#pragma unroll
    for (int t6 = 0; t6 < NT; ++t6)
        whh[t6] = ((const f16x8*)WhFhi)[(layer * NT + t6) * 64 + lane];
    if (layer > 0) {
#pragma unroll
        for (int t6 = 0; t6 < NT; ++t6)
            wih[t6] = ((const f16x8*)WiFhi)[((layer - 1) * NT + t6) * 64 + lane];
    }

    // pre-scaled biases in C/D layout (row = t6*16 + g*4 + r)
    f32x4 bc[4], bxn[2], bhn[2];
    {
        const int rb = g * 4;
#pragma unroll
        for (int t6 = 0; t6 < 4; ++t6)
#pragma unroll
            for (int r = 0; r < 4; ++r) {
                int row = t6 * 16 + rb + r;
                bc[t6][r] = -S1 * (bih[layer * 96 + row] + bhh[layer * 96 + row]);
            }
#pragma unroll
        for (int tt = 0; tt < 2; ++tt)
#pragma unroll
            for (int r = 0; r < 4; ++r) {
                int row = 64 + tt * 16 + rb + r;
                bxn[tt][r] = -2.0f * S1 * bih[layer * 96 + row];
                bhn[tt][r] = -2.0f * S1 * bhh[layer * 96 + row];
            }
        if (layer == 0) {
            // layer-0 wave never uses wih as frags: reuse for pre-scaled f32
            // input weights via the union view
#pragma unroll
            for (int t6 = 0; t6 < NT; ++t6) {
                FragU u;
#pragma unroll
                for (int r = 0; r < 4; ++r) {
                    int row = t6 * 16 + rb + r;
                    float s = (row < 64) ? -S1 : -2.0f * S1;
                    u.f[r] = s * Wih0[row];
                }
                wih[t6] = u.h;
            }
        }
    }

    float hp[2][8];
#pragma unroll
    for (int gr = 0; gr < 2; ++gr)
#pragma unroll
        for (int i = 0; i < 8; ++i) hp[gr][i] = 0.0f;
    f16x8 hfH[2] = {{0,0,0,0,0,0,0,0},{0,0,0,0,0,0,0,0}};

    // unified slot offset (read & write identical): row b, logical block g,
    // XOR-swizzled by (b>>1)&3.  Group gr adds gr*1024.
    const int soff = b * 64 + ((g ^ ((b >> 1) & 3)) << 4);
    unsigned char* const sbase = (unsigned char*)slot;

    // one GRU step for BOTH batch groups.  rq = producer parity to read,
    // wp = parity to write, st = step slot (0..3).
    auto do_step2 = [&](int t, int rq, int wp, int st) {
        f32x4 acc[2][4], accX[2][2], accH[2][2];
        // both handoff LDS reads first; latency hides under own-h MFMAs
        f16x8 iH[2];
        if (layer > 0) {
            const unsigned char* ru = sbase + (((layer - 1) * 8 + rq * 4 + st) << 11);
            if (grmask & 1) iH[0] = *(const f16x8*)(ru + soff);
            if (grmask & 2) iH[1] = *(const f16x8*)(ru + 1024 + soff);
        }
        // ---- MFMA phase: single product own-h (C-init = biases) ----
        __builtin_amdgcn_s_setprio(1);
#pragma unroll
        for (int gr = 0; gr < 2; ++gr)
            if (grmask & (1 << gr)) {
#pragma unroll
                for (int t6 = 0; t6 < 4; ++t6)
                    acc[gr][t6] = __builtin_amdgcn_mfma_f32_16x16x32_f16(whh[t6], hfH[gr], bc[t6], 0, 0, 0);
#pragma unroll
                for (int tt = 0; tt < 2; ++tt)
                    accH[gr][tt] = __builtin_amdgcn_mfma_f32_16x16x32_f16(whh[4 + tt], hfH[gr], bhn[tt], 0, 0, 0);
            }
        // input product: wih x iH (hi-only handoff) / scalar x for layer 0
        if (layer == 0) {
#pragma unroll
            for (int gr = 0; gr < 2; ++gr)
                if (grmask & (1 << gr)) {
                    float xv = xt[t][gr * 16 + b];
#pragma unroll
                    for (int t6 = 0; t6 < 4; ++t6) {
                        FragU u; u.h = wih[t6];
#pragma unroll
                        for (int r = 0; r < 4; ++r)
                            acc[gr][t6][r] = fmaf(u.f[r], xv, acc[gr][t6][r]);
                    }
#pragma unroll
                    for (int tt = 0; tt < 2; ++tt) {
                        FragU u; u.h = wih[4 + tt];
#pragma unroll
                        for (int r = 0; r < 4; ++r)
                            accX[gr][tt][r] = fmaf(u.f[r], xv, bxn[tt][r]);
                    }
                }
        } else {
#pragma unroll
            for (int gr = 0; gr < 2; ++gr)
                if (grmask & (1 << gr)) {
#pragma unroll
                    for (int t6 = 0; t6 < 4; ++t6)
                        acc[gr][t6] = __builtin_amdgcn_mfma_f32_16x16x32_f16(wih[t6], iH[gr], acc[gr][t6], 0, 0, 0);
#pragma unroll
                    for (int tt = 0; tt < 2; ++tt)
                        accX[gr][tt] = __builtin_amdgcn_mfma_f32_16x16x32_f16(wih[4 + tt], iH[gr], bxn[tt], 0, 0, 0);
                }
        }
        __builtin_amdgcn_s_setprio(0);
        // ---- gate phase: both groups together (16 independent chains) ----
        // gates (pre-scaled): Er=e^-rpre, Ez=e^-zpre, En=e^-2npre
        // r = 1/(1+Er); n = (1-En)/(1+En); h = [n*Ez + hp] / (1+Ez)
#pragma unroll
        for (int gr = 0; gr < 2; ++gr)
            if (grmask & (1 << gr)) {
#pragma unroll
                for (int jj = 0; jj < 2; ++jj)
#pragma unroll
                    for (int r = 0; r < 4; ++r) {
                        float Er = exp2b(acc[gr][jj][r]);
                        float Ez = exp2b(acc[gr][2 + jj][r]);
                        float rg = rcpa(1.0f + Er);
                        float u  = fmaf(rg, accH[gr][jj][r], accX[gr][jj][r]);
                        float En = exp2b(u);
                        float en1 = 1.0f + En, ez1 = 1.0f + Ez;
                        float d   = rcpa(en1 * ez1);
                        float t2  = fmaf(-En, Ez, Ez);        // (1-En)*Ez, single-rounded
                        float num = fmaf(hp[gr][jj * 4 + r], en1, t2);
                        hp[gr][jj * 4 + r] = num * d;
                    }
            }
        // ---- pack + handoff write, both groups (hi only, no residual) ----
#pragma unroll
        for (int gr = 0; gr < 2; ++gr)
            if (grmask & (1 << gr)) {
                unsigned int h01 = pk16(hp[gr][0], hp[gr][1]);
                unsigned int h23 = pk16(hp[gr][2], hp[gr][3]);
                unsigned int h45 = pk16(hp[gr][4], hp[gr][5]);
                unsigned int h67 = pk16(hp[gr][6], hp[gr][7]);
                FragU Hu;
                Hu.u[0] = h01; Hu.u[1] = h23; Hu.u[2] = h45; Hu.u[3] = h67;
                hfH[gr] = Hu.h;
                if (layer < L - 1) {
                    unsigned char* wp8 = sbase + ((layer * 8 + wp * 4 + st) << 11) + gr * 1024;
                    *(uint4*)(wp8 + soff) = make_uint4(h01, h23, h45, h67);
                }
            }
    };

    __syncthreads();

    for (int i = 0; i < NK; ++i) {
        int k = i - layer;            // local 4-step chunk index
        if (0 <= k && k < NPAIR) {
            const int p = i & 1, q = p ^ 1;
#pragma unroll
            for (int st = 0; st < 4; ++st)
                do_step2(4 * k + st, q, p, st);
        }
        __syncthreads();
    }

    // heads: per-(layer,group) partial over 32 hidden units, then cross-wave reduce
    {
        const int rb = g * 4;
#pragma unroll
        for (int hd = 0; hd < 3; ++hd) {
            const float* W = (hd == 0) ? Wk : (hd == 1) ? We : Wt;
#pragma unroll
            for (int gr = 0; gr < 2; ++gr)
                if (grmask & (1 << gr)) {
                    float s = 0.0f;
#pragma unroll
                    for (int jj = 0; jj < 2; ++jj)
#pragma unroll
                        for (int r = 0; r < 4; ++r)
                            s = fmaf(W[layer * H + jj * 16 + rb + r], hp[gr][jj * 4 + r], s);
                    s += __shfl_xor(s, 16, 64);
                    s += __shfl_xor(s, 32, 64);
                    if (g == 0) hpart[layer][hd][gr * 16 + b] = s;
                }
        }
        __syncthreads();
        if (wv < 3 && lane < BT) {
            int bb = lane;
            float s = (wv == 0) ? bk[0] : (wv == 1) ? be[0] : bt[0];
#pragma unroll
            for (int l = 0; l < L; ++l) s += hpart[l][wv][bb];
            out[wv * B + b0 + bb] = s;
        }
    }
}

extern "C" void kernel_launch(void* const* d_in, const int* in_sizes, int n_in,
                              void* d_out, int out_size, void* d_ws, size_t ws_size,
                              hipStream_t stream)
{
    const float* x    = (const float*)d_in[0];
    const float* Wih0 = (const float*)d_in[1];
    const float* Wih  = (const float*)d_in[2];
    const float* Whh  = (const float*)d_in[3];
    const float* bih  = (const float*)d_in[4];
    const float* bhh  = (const float*)d_in[5];
    const float* Wk   = (const float*)d_in[6];
    const float* bk   = (const float*)d_in[7];
    const float* We   = (const float*)d_in[8];
    const float* be   = (const float*)d_in[9];
    const float* Wt   = (const float*)d_in[10];
    const float* bt   = (const float*)d_in[11];
    float* out = (float*)d_out;

    const int B = in_sizes[0] / T_LEN;   // 16384

    unsigned short* WhFhi = (unsigned short*)d_ws;        // 6*6*64*8 f16
    unsigned short* WiFhi = WhFhi + L * NT * 64 * 8;      // 5*6*64*8 f16

    const int nPack = (L * NT * 64) + ((L - 1) * NT * 64);  // 4224
    pack_frags<<<(nPack + 255) / 256, 256, 0, stream>>>(Whh, Wih, WhFhi, WiFhi);
    gru_mfma<<<B / BT, TPB, 0, stream>>>(x, Wih0, bih, bhh, WhFhi, WiFhi,
                                         Wk, bk, We, be, Wt, bt, out, B);
}

// Round 16
// 235.983 us; speedup vs baseline: 1.1423x; 1.0064x over previous
//
#include <hip/hip_runtime.h>

#define T_LEN 100
#define H 32
#define L 6
#define NT 6          // 96 gate rows / 16
#define TPB 512       // 8 waves: SIMD s hosts waves {s, s+4}
#define BT 64         // TWO 32-batch tiles per block (4x16 groups); grid = B/64, 1 round
#define NPAIR 50      // two timesteps per barrier interval
#define NK (NPAIR + L - 1)   // 55 intervals, layer skew d = layer
#define S1 1.44269504088896f   // log2(e)

typedef float f32x4  __attribute__((ext_vector_type(4)));
typedef _Float16 f16x8 __attribute__((ext_vector_type(8)));

union FragU { f16x8 h; f32x4 f; unsigned int u[4]; };

__device__ inline unsigned short f2h(float f) {
    union { _Float16 h; unsigned short u; } v; v.h = (_Float16)f; return v.u;
}
__device__ inline float rcpa(float x)  { return __builtin_amdgcn_rcpf(x); }
__device__ inline float exp2b(float x) { return __builtin_amdgcn_exp2f(x); }

// pack f32 pair -> one u32 of 2 f16 (RTZ)
__device__ inline unsigned int pk16(float a, float b) {
    unsigned int h;
    asm("v_cvt_pkrtz_f16_f32 %0, %1, %2" : "=v"(h) : "v"(a), "v"(b));
    return h;
}

// ---- prep: pack weight A-fragments as f16 (matmul-operand quantization;
// the f32 recurrent state hp is never quantized), pre-scaled by -log2e /
// -2log2e, with kappa k-relabeling: hardware k-slot (gk*8+e) holds W column
// j = (e>>2)*16 + gk*4 + (e&3).  This makes MFMA C/D layout == B-frag layout.
__global__ void pack_frags(const float* __restrict__ Whh, const float* __restrict__ Wih,
                           unsigned short* __restrict__ WhFhi,
                           unsigned short* __restrict__ WiFhi)
{
    int tid = blockIdx.x * blockDim.x + threadIdx.x;
    const int NWH = L * NT * 64;          // 2304
    const int NWI = (L - 1) * NT * 64;    // 1920
    if (tid >= NWH + NWI) return;
    const float* src; unsigned short *dhi; int tile, lane;
    if (tid < NWH) {
        int l = tid / (NT * 64); int r = tid % (NT * 64); tile = r / 64; lane = r % 64;
        src = Whh + l * 96 * H;
        dhi = WhFhi + tid * 8;
    } else {
        int t2 = tid - NWH;
        int l = t2 / (NT * 64); int r = t2 % (NT * 64); tile = r / 64; lane = r % 64;
        src = Wih + l * 96 * H;           // W_ih[l] feeds layer l+1
        dhi = WiFhi + t2 * 8;
    }
    int row = tile * 16 + (lane & 15);
    int gk  = lane >> 4;
    float scale = (row < 64) ? -S1 : -2.0f * S1;
    unsigned short thi[8];
#pragma unroll
    for (int e = 0; e < 8; ++e) {
        int j = ((e >> 2) << 4) + (gk << 2) + (e & 3);   // kappa^-1
        thi[e] = f2h(scale * src[row * H + j]);
    }
    *(uint4*)dhi = *(const uint4*)thi;
}

// ---- main: 8-wave layer ladder, barrier-synced, two steps per interval,
// single-product f16 matmuls, setprio(1) around the MFMA phase, and TWO
// INDEPENDENT BATCH TILES per block (grid halved to one round).  Each wave
// keeps one layer's weights but advances two independent recurrences; the
// tile bodies are sequential straight-line code, so the compiler's own
// scheduler may hoist tile-B MFMAs into tile-A gate stalls (it beat every
// forced pipeline; give it independent work instead of forced order).
// VALU-balanced wave map: SIMD pairs {L0,L1a} {L2,L1b} {L3,L5a} {L4,L5b}.
__global__ __launch_bounds__(TPB, 2) void gru_mfma(
    const float* __restrict__ x,          // [B][T]
    const float* __restrict__ Wih0,       // [96]
    const float* __restrict__ bih,        // [6][96]
    const float* __restrict__ bhh,        // [6][96]
    const unsigned short* __restrict__ WhFhi,
    const unsigned short* __restrict__ WiFhi,
    const float* __restrict__ Wk, const float* __restrict__ bk,
    const float* __restrict__ We, const float* __restrict__ be,
    const float* __restrict__ Wt, const float* __restrict__ bt,
    float* __restrict__ out, int B)
{
    // handoff slot per (layer 0..4, interval parity, step 0/1), 4 KB each:
    // tile{0,1} x grp{0,1} x 1 KB.  row b = 64B; logical 16B-block c stored
    // at column c ^ ((b>>1)&3).
    __shared__ unsigned char slot[5][2][2][4096];   // 80 KB
    __shared__ float xt[T_LEN][BT];                 // 25.6 KB
    __shared__ float hpart[L][3][BT];               // 4.6 KB

    const int tid  = threadIdx.x;
    const int wv   = tid >> 6;        // wave index
    const int lane = tid & 63;
    const int b    = lane & 15;       // batch col (MFMA N)
    const int g    = lane >> 4;       // k-group
    const int b0   = blockIdx.x * 32; // per-tile batch base
    const int HALF = B >> 1;          // tile1 batches start at B/2

    // wave -> (layer, group-mask).  SIMD pairs {w0,w4} {w1,w5} {w2,w6}
    // {w3,w7}; L1 and L5 split in half so every SIMD carries 3 gate-units
    // per tile:  S0:{L0, L1.g0}  S1:{L2, L1.g1}  S2:{L3, L5.g0}  S3:{L4, L5.g1}
    int layer, grmask;
    switch (wv) {
      case 0: layer = 0; grmask = 3; break;   // light scalar-input layer
      case 4: layer = 1; grmask = 1; break;
      case 1: layer = 2; grmask = 3; break;
      case 5: layer = 1; grmask = 2; break;
      case 2: layer = 3; grmask = 3; break;
      case 6: layer = 5; grmask = 1; break;
      case 3: layer = 4; grmask = 3; break;
      default: layer = 5; grmask = 2; break;  // w7
    }

    // stage x tiles: cols 0-31 = tile0 (batches b0..), 32-63 = tile1 (HALF+b0..)
    for (int idx = tid; idx < T_LEN * BT; idx += TPB) {
        int bb = idx / T_LEN, t = idx % T_LEN;
        int batch = (bb < 32) ? (b0 + bb) : (HALF + b0 + bb - 32);
        xt[t][bb] = x[batch * T_LEN + t];
    }

    // weight fragments for my layer, held in registers all 100 steps
    f16x8 whh[NT], wih[NT];
#pragma unroll
    for (int t6 = 0; t6 < NT; ++t6)
        whh[t6] = ((const f16x8*)WhFhi)[(layer * NT + t6) * 64 + lane];
    if (layer > 0) {
#pragma unroll
        for (int t6 = 0; t6 < NT; ++t6)
            wih[t6] = ((const f16x8*)WiFhi)[((layer - 1) * NT + t6) * 64 + lane];
    }

    // pre-scaled biases in C/D layout (row = t6*16 + g*4 + r)
    f32x4 bc[4], bxn[2], bhn[2];
    {
        const int rb = g * 4;
#pragma unroll
        for (int t6 = 0; t6 < 4; ++t6)
#pragma unroll
            for (int r = 0; r < 4; ++r) {
                int row = t6 * 16 + rb + r;
                bc[t6][r] = -S1 * (bih[layer * 96 + row] + bhh[layer * 96 + row]);
            }
#pragma unroll
        for (int tt = 0; tt < 2; ++tt)
#pragma unroll
            for (int r = 0; r < 4; ++r) {
                int row = 64 + tt * 16 + rb + r;
                bxn[tt][r] = -2.0f * S1 * bih[layer * 96 + row];
                bhn[tt][r] = -2.0f * S1 * bhh[layer * 96 + row];
            }
        if (layer == 0) {
            // layer-0 wave never uses wih as frags: reuse for pre-scaled f32
            // input weights via the union view
#pragma unroll
            for (int t6 = 0; t6 < NT; ++t6) {
                FragU u;
#pragma unroll
                for (int r = 0; r < 4; ++r) {
                    int row = t6 * 16 + rb + r;
                    float s = (row < 64) ? -S1 : -2.0f * S1;
                    u.f[r] = s * Wih0[row];
                }
                wih[t6] = u.h;
            }
        }
    }

    float hp[2][2][8];                 // [tile][group][elem], f32, never quantized
#pragma unroll
    for (int tl = 0; tl < 2; ++tl)
#pragma unroll
        for (int gr = 0; gr < 2; ++gr)
#pragma unroll
            for (int i = 0; i < 8; ++i) hp[tl][gr][i] = 0.0f;
    f16x8 hfH[2][2] = {{{0,0,0,0,0,0,0,0},{0,0,0,0,0,0,0,0}},
                       {{0,0,0,0,0,0,0,0},{0,0,0,0,0,0,0,0}}};

    // unified slot offset (read & write identical): row b, logical block g,
    // XOR-swizzled by (b>>1)&3.  Tile adds tl*2048, group adds gr*1024.
    const int soff = b * 64 + ((g ^ ((b >> 1) & 3)) << 4);
    unsigned char* const sbase = (unsigned char*)slot;

    // one GRU step for ONE tile (both groups).  rq = producer parity to
    // read, wp = parity to write, st = step slot (0/1), tl = tile (literal).
    auto do_step2 = [&](int t, int rq, int wp, int st, int tl) {
        f32x4 acc[2][4], accX[2][2], accH[2][2];
        // both handoff LDS reads first; latency hides under own-h MFMAs
        f16x8 iH[2];
        if (layer > 0) {
            const unsigned char* ru = sbase + (((layer - 1) * 4 + rq * 2 + st) << 12) + tl * 2048;
            if (grmask & 1) iH[0] = *(const f16x8*)(ru + soff);
            if (grmask & 2) iH[1] = *(const f16x8*)(ru + 1024 + soff);
        }
        // ---- MFMA phase: single product own-h (C-init = biases) ----
        __builtin_amdgcn_s_setprio(1);
#pragma unroll
        for (int gr = 0; gr < 2; ++gr)
            if (grmask & (1 << gr)) {
#pragma unroll
                for (int t6 = 0; t6 < 4; ++t6)
                    acc[gr][t6] = __builtin_amdgcn_mfma_f32_16x16x32_f16(whh[t6], hfH[tl][gr], bc[t6], 0, 0, 0);
#pragma unroll
                for (int tt = 0; tt < 2; ++tt)
                    accH[gr][tt] = __builtin_amdgcn_mfma_f32_16x16x32_f16(whh[4 + tt], hfH[tl][gr], bhn[tt], 0, 0, 0);
            }
        // input product: wih x iH (hi-only handoff) / scalar x for layer 0
        if (layer == 0) {
#pragma unroll
            for (int gr = 0; gr < 2; ++gr)
                if (grmask & (1 << gr)) {
                    float xv = xt[t][tl * 32 + gr * 16 + b];
#pragma unroll
                    for (int t6 = 0; t6 < 4; ++t6) {
                        FragU u; u.h = wih[t6];
#pragma unroll
                        for (int r = 0; r < 4; ++r)
                            acc[gr][t6][r] = fmaf(u.f[r], xv, acc[gr][t6][r]);
                    }
#pragma unroll
                    for (int tt = 0; tt < 2; ++tt) {
                        FragU u; u.h = wih[4 + tt];
#pragma unroll
                        for (int r = 0; r < 4; ++r)
                            accX[gr][tt][r] = fmaf(u.f[r], xv, bxn[tt][r]);
                    }
                }
        } else {
#pragma unroll
            for (int gr = 0; gr < 2; ++gr)
                if (grmask & (1 << gr)) {
#pragma unroll
                    for (int t6 = 0; t6 < 4; ++t6)
                        acc[gr][t6] = __builtin_amdgcn_mfma_f32_16x16x32_f16(wih[t6], iH[gr], acc[gr][t6], 0, 0, 0);
#pragma unroll
                    for (int tt = 0; tt < 2; ++tt)
                        accX[gr][tt] = __builtin_amdgcn_mfma_f32_16x16x32_f16(wih[4 + tt], iH[gr], bxn[tt], 0, 0, 0);
                }
        }
        __builtin_amdgcn_s_setprio(0);
        // ---- gate phase ----
        // gates (pre-scaled): Er=e^-rpre, Ez=e^-zpre, En=e^-2npre
        // r = 1/(1+Er); n = (1-En)/(1+En); h = [n*Ez + hp] / (1+Ez)
#pragma unroll
        for (int gr = 0; gr < 2; ++gr)
            if (grmask & (1 << gr)) {
#pragma unroll
                for (int jj = 0; jj < 2; ++jj)
#pragma unroll
                    for (int r = 0; r < 4; ++r) {
                        float Er = exp2b(acc[gr][jj][r]);
                        float Ez = exp2b(acc[gr][2 + jj][r]);
                        float rg = rcpa(1.0f + Er);
                        float u  = fmaf(rg, accH[gr][jj][r], accX[gr][jj][r]);
                        float En = exp2b(u);
                        float en1 = 1.0f + En, ez1 = 1.0f + Ez;
                        float d   = rcpa(en1 * ez1);
                        float t2  = fmaf(-En, Ez, Ez);        // (1-En)*Ez, single-rounded
                        float num = fmaf(hp[tl][gr][jj * 4 + r], en1, t2);
                        hp[tl][gr][jj * 4 + r] = num * d;
                    }
            }
        // ---- pack + handoff write (hi only) ----
#pragma unroll
        for (int gr = 0; gr < 2; ++gr)
            if (grmask & (1 << gr)) {
                unsigned int h01 = pk16(hp[tl][gr][0], hp[tl][gr][1]);
                unsigned int h23 = pk16(hp[tl][gr][2], hp[tl][gr][3]);
                unsigned int h45 = pk16(hp[tl][gr][4], hp[tl][gr][5]);
                unsigned int h67 = pk16(hp[tl][gr][6], hp[tl][gr][7]);
                FragU Hu;
                Hu.u[0] = h01; Hu.u[1] = h23; Hu.u[2] = h45; Hu.u[3] = h67;
                hfH[tl][gr] = Hu.h;
                if (layer < L - 1) {
                    unsigned char* wp8 = sbase + ((layer * 4 + wp * 2 + st) << 12) + tl * 2048 + gr * 1024;
                    *(uint4*)(wp8 + soff) = make_uint4(h01, h23, h45, h67);
                }
            }
    };

    __syncthreads();

    for (int i = 0; i < NK; ++i) {
        int k = i - layer;            // local 2-step chunk index
        if (0 <= k && k < NPAIR) {
            const int p = i & 1, q = p ^ 1;
            // tile bodies sequential; tiles are independent recurrences, so
            // the scheduler may overlap tile-B MFMAs with tile-A gates
            do_step2(2 * k,     q, p, 0, 0);
            do_step2(2 * k,     q, p, 0, 1);
            do_step2(2 * k + 1, q, p, 1, 0);
            do_step2(2 * k + 1, q, p, 1, 1);
        }
        __syncthreads();
    }

    // heads: per-(layer,tile,group) partial over 32 hidden units, then reduce
    {
        const int rb = g * 4;
#pragma unroll
        for (int hd = 0; hd < 3; ++hd) {
            const float* W = (hd == 0) ? Wk : (hd == 1) ? We : Wt;
#pragma unroll
            for (int tl = 0; tl < 2; ++tl)
#pragma unroll
                for (int gr = 0; gr < 2; ++gr)
                    if (grmask & (1 << gr)) {
                        float s = 0.0f;
#pragma unroll
                        for (int jj = 0; jj < 2; ++jj)
#pragma unroll
                            for (int r = 0; r < 4; ++r)
                                s = fmaf(W[layer * H + jj * 16 + rb + r], hp[tl][gr][jj * 4 + r], s);
                        s += __shfl_xor(s, 16, 64);
                        s += __shfl_xor(s, 32, 64);
                        if (g == 0) hpart[layer][hd][tl * 32 + gr * 16 + b] = s;
                    }
        }
        __syncthreads();
        if (wv < 3 && lane < BT) {
            int bb = lane;
            int batch = (bb < 32) ? (b0 + bb) : (HALF + b0 + bb - 32);
            float s = (wv == 0) ? bk[0] : (wv == 1) ? be[0] : bt[0];
#pragma unroll
            for (int l = 0; l < L; ++l) s += hpart[l][wv][bb];
            out[wv * B + batch] = s;
        }
    }
}

extern "C" void kernel_launch(void* const* d_in, const int* in_sizes, int n_in,
                              void* d_out, int out_size, void* d_ws, size_t ws_size,
                              hipStream_t stream)
{
    const float* x    = (const float*)d_in[0];
    const float* Wih0 = (const float*)d_in[1];
    const float* Wih  = (const float*)d_in[2];
    const float* Whh  = (const float*)d_in[3];
    const float* bih  = (const float*)d_in[4];
    const float* bhh  = (const float*)d_in[5];
    const float* Wk   = (const float*)d_in[6];
    const float* bk   = (const float*)d_in[7];
    const float* We   = (const float*)d_in[8];
    const float* be   = (const float*)d_in[9];
    const float* Wt   = (const float*)d_in[10];
    const float* bt   = (const float*)d_in[11];
    float* out = (float*)d_out;

    const int B = in_sizes[0] / T_LEN;   // 16384

    unsigned short* WhFhi = (unsigned short*)d_ws;        // 6*6*64*8 f16
    unsigned short* WiFhi = WhFhi + L * NT * 64 * 8;      // 5*6*64*8 f16

    const int nPack = (L * NT * 64) + ((L - 1) * NT * 64);  // 4224
    pack_frags<<<(nPack + 255) / 256, 256, 0, stream>>>(Whh, Wih, WhFhi, WiFhi);
    gru_mfma<<<B / BT, TPB, 0, stream>>>(x, Wih0, bih, bhh, WhFhi, WiFhi,
                                         Wk, bk, We, be, Wt, bt, out, B);
}